// Round 2
// baseline (1456.098 us; speedup 1.0000x reference)
//
#include <hip/hip_runtime.h>
#include <hip/hip_bf16.h>
#include <math.h>
#include <stdint.h>

#define OUTW 240  // 128 + 64 + 32 + 16
#define CAP 1024  // per-wave LDS att buffer (max degree supported on fast path)

__device__ __forceinline__ float lrelu(float x) { return x > 0.f ? x : 0.01f * x; }

// ---------------- cos/sin table (interleaved float2): R*64 entries ----------------
__global__ __launch_bounds__(256) void cossin_kernel(const float* __restrict__ rel,
                                                     float2* __restrict__ ctab, int n) {
    int i = blockIdx.x * blockDim.x + threadIdx.x;
    if (i >= n) return;
    const float PHASE_SCALE = (float)(3.1415926235897933 / ((12.0 + 2.0) / 64.0));
    float p = rel[i] * PHASE_SCALE;
    ctab[i] = make_float2(cosf(p), sinf(p));
}

// ---------------- histogram of dst ----------------
__global__ __launch_bounds__(256) void hist_kernel(const int* __restrict__ dst, int* __restrict__ deg, int E) {
    int e = blockIdx.x * blockDim.x + threadIdx.x;
    if (e >= E) return;
    atomicAdd(&deg[dst[e]], 1);
}

// ---------------- 3-kernel exclusive scan over N (offsets) ----------------
__global__ __launch_bounds__(1024) void scan_partial(const int* __restrict__ deg, int* __restrict__ incl,
                                                     int* __restrict__ bsum, int n) {
    __shared__ int sm[1024];
    int i = blockIdx.x * 1024 + threadIdx.x;
    int x = (i < n) ? deg[i] : 0;
    sm[threadIdx.x] = x;
    __syncthreads();
    for (int off = 1; off < 1024; off <<= 1) {
        int y = (threadIdx.x >= off) ? sm[threadIdx.x - off] : 0;
        __syncthreads();
        sm[threadIdx.x] += y;
        __syncthreads();
    }
    if (i < n) incl[i] = sm[threadIdx.x];
    if (threadIdx.x == 1023) bsum[blockIdx.x] = sm[1023];
}

__global__ __launch_bounds__(128) void scan_bsums(const int* __restrict__ bsum, int* __restrict__ bbase, int nb) {
    __shared__ int sm[128];
    int t = threadIdx.x;
    int x = (t < nb) ? bsum[t] : 0;
    sm[t] = x;
    __syncthreads();
    for (int off = 1; off < 128; off <<= 1) {
        int y = (t >= off) ? sm[t - off] : 0;
        __syncthreads();
        sm[t] += y;
        __syncthreads();
    }
    if (t < nb) bbase[t] = sm[t] - x;  // exclusive
}

__global__ __launch_bounds__(1024) void scan_final(const int* __restrict__ incl, const int* __restrict__ bbase,
                                                   int* __restrict__ offs, int n) {
    int i = blockIdx.x * 1024 + threadIdx.x;
    if (i < n) offs[i + 1] = incl[i] + bbase[blockIdx.x];
    if (i == 0) offs[0] = 0;
}

// ---------------- CSR fill: src + type in CSR-by-dst order ----------------
__global__ __launch_bounds__(256) void fill_kernel(const int* __restrict__ src, const int* __restrict__ dst,
                                                   const int* __restrict__ typ, const int* __restrict__ offs,
                                                   int* __restrict__ cur, int* __restrict__ esrc,
                                                   int* __restrict__ etyp, int E) {
    int e = blockIdx.x * blockDim.x + threadIdx.x;
    if (e >= E) return;
    int d = dst[e];
    int pos = offs[d] + atomicAdd(&cur[d], 1);
    esrc[pos] = src[e];
    etyp[pos] = typ[e];
}

// ---------------- fused: RotatE att + edge softmax + layer-0 side (one gather pass) ----------------
// One wave per node. Online softmax: running max m, running sum ssum, rescaled
// accumulators acc0/acc1. Raw att scores parked in LDS (volatile, wave-sync) for
// the final normalized-ews write; global fallback for len > CAP (never hit here).
__global__ __launch_bounds__(256) void fused_att_kernel(const float* __restrict__ ent,
                                                        const float2* __restrict__ ctab,
                                                        const int* __restrict__ offs,
                                                        const int* __restrict__ esrc,
                                                        const int* __restrict__ etyp,
                                                        float* __restrict__ ews,
                                                        float* __restrict__ side, int n) {
    __shared__ float smAtt[4][CAP];
    int wIdx = threadIdx.x >> 6, lane = threadIdx.x & 63;
    int v = blockIdx.x * 4 + wIdx;
    if (v >= n) return;
    int b = offs[v];
    int len = offs[v + 1] - b;
    if (len == 0) {  // side must still be zero (ws is poisoned)
        side[(size_t)v * 128 + lane] = 0.f;
        side[(size_t)v * 128 + 64 + lane] = 0.f;
        return;
    }
    float re_t = ent[(size_t)v * 128 + lane];
    float im_t = ent[(size_t)v * 128 + 64 + lane];
    volatile float* sm = smAtt[wIdx];
    const bool fits = (len <= CAP);
    float m = -3.4e38f, ssum = 0.f, acc0 = 0.f, acc1 = 0.f;
    for (int p = 0; p < len; ++p) {
        int s = esrc[b + p];
        int r = etyp[b + p];
        const float* h = ent + (size_t)s * 128;
        float re_h = h[lane], im_h = h[64 + lane];
        float2 cs = ctab[r * 64 + lane];
        float re_s = re_h * cs.x - im_h * cs.y - re_t;
        float im_s = re_h * cs.y + im_h * cs.x - im_t;
        float a = sqrtf(re_s * re_s + im_s * im_s);
#pragma unroll
        for (int o = 32; o; o >>= 1) a += __shfl_xor(a, o);  // butterfly: all lanes hold total
        if (lane == 0) {
            if (fits) sm[p] = a;
            else ews[b + p] = a;  // raw score parking (fallback)
        }
        if (a > m) {  // wave-uniform branch (a uniform after butterfly)
            float corr = __expf(m - a);
            ssum *= corr;
            acc0 *= corr;
            acc1 *= corr;
            m = a;
        }
        float e = __expf(a - m);
        ssum += e;
        acc0 += e * re_h;
        acc1 += e * im_h;
    }
    float inv = 1.f / ssum;
    side[(size_t)v * 128 + lane] = acc0 * inv;
    side[(size_t)v * 128 + 64 + lane] = acc1 * inv;
    if (fits) {
        for (int p = lane; p < len; p += 64) ews[b + p] = __expf(sm[p] - m) * inv;
    } else {
        __threadfence();
        for (int p = lane; p < len; p += 64) ews[b + p] = __expf(ews[b + p] - m) * inv;
    }
}

// ---------------- side = segment_sum(ews * ego[src]) for layers 1,2: one wave per node ----------------
template <int DIN>
__global__ __launch_bounds__(256) void side_kernel(const float* __restrict__ ego, const float* __restrict__ ews,
                                                   const int* __restrict__ esrc, const int* __restrict__ offs,
                                                   float* __restrict__ side, int n) {
    int gid = blockIdx.x * blockDim.x + threadIdx.x;
    int wid = gid >> 6, lane = gid & 63;
    if (wid >= n) return;
    int v = wid;
    float acc = 0.f;
    int b = offs[v], e2 = offs[v + 1];
    for (int p = b; p < e2; ++p) {
        float w = ews[p];
        int s = esrc[p];
        if (lane < DIN) acc += w * ego[(size_t)s * DIN + lane];
    }
    if (lane < DIN) side[(size_t)v * DIN + lane] = acc;
}

// ---------------- fused layer: out1+out2, leaky relu, row-norm write ----------------
template <int DIN, int DOUT>
__global__ __launch_bounds__(256) void layer_kernel(const float* __restrict__ ego, const float* __restrict__ side,
                                                    const float* __restrict__ W1, const float* __restrict__ b1,
                                                    const float* __restrict__ W2, const float* __restrict__ b2,
                                                    float* __restrict__ ego_next, float* __restrict__ out,
                                                    int colOff, int n) {
    __shared__ float sW1[DIN * DOUT];
    __shared__ float sW2[DIN * DOUT];
    for (int i = threadIdx.x; i < DIN * DOUT; i += blockDim.x) {
        sW1[i] = W1[i];
        sW2[i] = W2[i];
    }
    __syncthreads();
    int gid = blockIdx.x * blockDim.x + threadIdx.x;
    int wid = gid >> 6, lane = gid & 63;
    int nw = (gridDim.x * blockDim.x) >> 6;
    int jj = lane < DOUT ? lane : DOUT - 1;
    float b1v = b1[jj], b2v = b2[jj];
    constexpr int K = (DIN + 63) / 64;
    for (int v = wid; v < n; v += nw) {
        float a[K], mm[K];
#pragma unroll
        for (int k = 0; k < K; ++k) {
            int d = k * 64 + lane;
            float e_ = 0.f, s_ = 0.f;
            if (d < DIN) {
                e_ = ego[(size_t)v * DIN + d];
                s_ = side[(size_t)v * DIN + d];
            }
            a[k] = e_ + s_;
            mm[k] = e_ * s_;
        }
        float o1 = b1v, o2 = b2v;
#pragma unroll
        for (int i = 0; i < DIN; ++i) {
            float av = __shfl(a[i >> 6], i & 63);
            float mv = __shfl(mm[i >> 6], i & 63);
            o1 += av * sW1[i * DOUT + jj];
            o2 += mv * sW2[i * DOUT + jj];
        }
        o1 = lrelu(o1);
        o2 = lrelu(o2);
        float eg = o1 + o2;
        float sq = (lane < DOUT) ? eg * eg : 0.f;
#pragma unroll
        for (int o = 32; o; o >>= 1) sq += __shfl_xor(sq, o);
        float inv = 1.f / fmaxf(sqrtf(sq), 1e-12f);
        if (lane < DOUT) {
            ego_next[(size_t)v * DOUT + lane] = eg;
            out[(size_t)v * OUTW + colOff + lane] = eg * inv;
        }
    }
}

// ---------------- copy ent_embed into out[:, 0:128] ----------------
__global__ __launch_bounds__(256) void copy_ent(const float4* __restrict__ ent4, float* __restrict__ out, int n) {
    int idx = blockIdx.x * blockDim.x + threadIdx.x;
    int total = n * 32;  // 128 floats = 32 float4 per row
    if (idx >= total) return;
    int v = idx >> 5, c = idx & 31;
    float4 x = ent4[idx];
    *(float4*)(out + (size_t)v * OUTW + c * 4) = x;
}

extern "C" void kernel_launch(void* const* d_in, const int* in_sizes, int n_in,
                              void* d_out, int out_size, void* d_ws, size_t ws_size,
                              hipStream_t stream) {
    const float* ent = (const float*)d_in[0];
    const float* rel = (const float*)d_in[1];
    const float* W1_0 = (const float*)d_in[2];
    const float* b1_0 = (const float*)d_in[3];
    const float* W2_0 = (const float*)d_in[4];
    const float* b2_0 = (const float*)d_in[5];
    const float* W1_1 = (const float*)d_in[6];
    const float* b1_1 = (const float*)d_in[7];
    const float* W2_1 = (const float*)d_in[8];
    const float* b2_1 = (const float*)d_in[9];
    const float* W1_2 = (const float*)d_in[10];
    const float* b1_2 = (const float*)d_in[11];
    const float* W2_2 = (const float*)d_in[12];
    const float* b2_2 = (const float*)d_in[13];
    const int* esrc_in = (const int*)d_in[14];
    const int* edst_in = (const int*)d_in[15];
    const int* etyp_in = (const int*)d_in[16];
    float* out = (float*)d_out;

    const int N = in_sizes[0] / 128;
    const int E = in_sizes[14];
    const int RD = in_sizes[1];  // R*64

    // ---- carve workspace ----
    char* p = (char*)d_ws;
    auto alloc = [&](size_t bytes) -> void* {
        void* r = (void*)p;
        p += (bytes + 255) & ~(size_t)255;
        return r;
    };
    float2* ctab = (float2*)alloc((size_t)RD * 8);
    float* ews = (float*)alloc((size_t)E * 4);
    int* esrc = (int*)alloc((size_t)E * 4);
    int* etyp = (int*)alloc((size_t)E * 4);
    int* deg = (int*)alloc((size_t)N * 4);
    int* cur = (int*)alloc((size_t)N * 4);
    int* incl = (int*)alloc((size_t)N * 4);
    int* offs = (int*)alloc((size_t)(N + 1) * 4);
    int* bsum = (int*)alloc(512);
    int* bbase = (int*)alloc(512);
    float* side = (float*)alloc((size_t)N * 128 * 4);
    float* ego1 = (float*)alloc((size_t)N * 64 * 4);
    float* ego2 = (float*)alloc((size_t)N * 32 * 4);
    float* ego3 = (float*)alloc((size_t)N * 16 * 4);

    // ---- zero atomic counters (ws is poisoned each launch) ----
    hipMemsetAsync(deg, 0, (size_t)N * 4, stream);
    hipMemsetAsync(cur, 0, (size_t)N * 4, stream);

    // ---- cos/sin table ----
    cossin_kernel<<<(RD + 255) / 256, 256, 0, stream>>>(rel, ctab, RD);

    // ---- CSR build ----
    hist_kernel<<<(E + 255) / 256, 256, 0, stream>>>(edst_in, deg, E);
    int nb1 = (N + 1023) / 1024;
    scan_partial<<<nb1, 1024, 0, stream>>>(deg, incl, bsum, N);
    scan_bsums<<<1, 128, 0, stream>>>(bsum, bbase, nb1);
    scan_final<<<nb1, 1024, 0, stream>>>(incl, bbase, offs, N);
    fill_kernel<<<(E + 255) / 256, 256, 0, stream>>>(esrc_in, edst_in, etyp_in, offs, cur, esrc, etyp, E);

    // ---- fused attention + softmax + layer-0 side (single gather pass) ----
    fused_att_kernel<<<(N + 3) / 4, 256, 0, stream>>>(ent, ctab, offs, esrc, etyp, ews, side, N);

    // ---- layer 0: din=128, dout=64 ----
    layer_kernel<128, 64><<<2048, 256, 0, stream>>>(ent, side, W1_0, b1_0, W2_0, b2_0, ego1, out, 128, N);

    // ---- layer 1: din=64, dout=32 ----
    side_kernel<64><<<(N + 3) / 4, 256, 0, stream>>>(ego1, ews, esrc, offs, side, N);
    layer_kernel<64, 32><<<2048, 256, 0, stream>>>(ego1, side, W1_1, b1_1, W2_1, b2_1, ego2, out, 192, N);

    // ---- layer 2: din=32, dout=16 ----
    side_kernel<32><<<(N + 3) / 4, 256, 0, stream>>>(ego2, ews, esrc, offs, side, N);
    layer_kernel<32, 16><<<2048, 256, 0, stream>>>(ego2, side, W1_2, b1_2, W2_2, b2_2, ego3, out, 224, N);

    // ---- out[:, 0:128] = ent_embed ----
    copy_ent<<<((N * 32) + 255) / 256, 256, 0, stream>>>((const float4*)ent, out, N);
}

// Round 3
// 1010.779 us; speedup vs baseline: 1.4406x; 1.4406x over previous
//
#include <hip/hip_runtime.h>
#include <hip/hip_bf16.h>
#include <math.h>
#include <stdint.h>

#define OUTW 240  // 128 + 64 + 32 + 16
#define CAP 1024  // per-wave LDS att buffer (max degree supported on fast path)

__device__ __forceinline__ float lrelu(float x) { return x > 0.f ? x : 0.01f * x; }

// ---------------- cos/sin table (interleaved float2): R*64 entries ----------------
__global__ __launch_bounds__(256) void cossin_kernel(const float* __restrict__ rel,
                                                     float2* __restrict__ ctab, int n) {
    int i = blockIdx.x * blockDim.x + threadIdx.x;
    if (i >= n) return;
    const float PHASE_SCALE = (float)(3.1415926235897933 / ((12.0 + 2.0) / 64.0));
    float p = rel[i] * PHASE_SCALE;
    ctab[i] = make_float2(cosf(p), sinf(p));
}

// ---------------- histogram of dst ----------------
__global__ __launch_bounds__(256) void hist_kernel(const int* __restrict__ dst, int* __restrict__ deg, int E) {
    int e = blockIdx.x * blockDim.x + threadIdx.x;
    if (e >= E) return;
    atomicAdd(&deg[dst[e]], 1);
}

// ---------------- 3-kernel exclusive scan over N (offsets) ----------------
__global__ __launch_bounds__(1024) void scan_partial(const int* __restrict__ deg, int* __restrict__ incl,
                                                     int* __restrict__ bsum, int n) {
    __shared__ int sm[1024];
    int i = blockIdx.x * 1024 + threadIdx.x;
    int x = (i < n) ? deg[i] : 0;
    sm[threadIdx.x] = x;
    __syncthreads();
    for (int off = 1; off < 1024; off <<= 1) {
        int y = (threadIdx.x >= off) ? sm[threadIdx.x - off] : 0;
        __syncthreads();
        sm[threadIdx.x] += y;
        __syncthreads();
    }
    if (i < n) incl[i] = sm[threadIdx.x];
    if (threadIdx.x == 1023) bsum[blockIdx.x] = sm[1023];
}

__global__ __launch_bounds__(128) void scan_bsums(const int* __restrict__ bsum, int* __restrict__ bbase, int nb) {
    __shared__ int sm[128];
    int t = threadIdx.x;
    int x = (t < nb) ? bsum[t] : 0;
    sm[t] = x;
    __syncthreads();
    for (int off = 1; off < 128; off <<= 1) {
        int y = (t >= off) ? sm[t - off] : 0;
        __syncthreads();
        sm[t] += y;
        __syncthreads();
    }
    if (t < nb) bbase[t] = sm[t] - x;  // exclusive
}

__global__ __launch_bounds__(1024) void scan_final(const int* __restrict__ incl, const int* __restrict__ bbase,
                                                   int* __restrict__ offs, int n) {
    int i = blockIdx.x * 1024 + threadIdx.x;
    if (i < n) offs[i + 1] = incl[i] + bbase[blockIdx.x];
    if (i == 0) offs[0] = 0;
}

// ---------------- CSR fill: src + type in CSR-by-dst order ----------------
__global__ __launch_bounds__(256) void fill_kernel(const int* __restrict__ src, const int* __restrict__ dst,
                                                   const int* __restrict__ typ, const int* __restrict__ offs,
                                                   int* __restrict__ cur, int* __restrict__ esrc,
                                                   int* __restrict__ etyp, int E) {
    int e = blockIdx.x * blockDim.x + threadIdx.x;
    if (e >= E) return;
    int d = dst[e];
    int pos = offs[d] + atomicAdd(&cur[d], 1);
    esrc[pos] = src[e];
    etyp[pos] = typ[e];
}

// ---------------- fused: RotatE att + edge softmax + layer-0 side (one gather pass) ----------------
__global__ __launch_bounds__(256) void fused_att_kernel(const float* __restrict__ ent,
                                                        const float2* __restrict__ ctab,
                                                        const int* __restrict__ offs,
                                                        const int* __restrict__ esrc,
                                                        const int* __restrict__ etyp,
                                                        float* __restrict__ ews,
                                                        float* __restrict__ side, int n) {
    __shared__ float smAtt[4][CAP];
    int wIdx = threadIdx.x >> 6, lane = threadIdx.x & 63;
    int v = blockIdx.x * 4 + wIdx;
    if (v >= n) return;
    int b = offs[v];
    int len = offs[v + 1] - b;
    if (len == 0) {  // side must still be zero (ws is poisoned)
        side[(size_t)v * 128 + lane] = 0.f;
        side[(size_t)v * 128 + 64 + lane] = 0.f;
        return;
    }
    float re_t = ent[(size_t)v * 128 + lane];
    float im_t = ent[(size_t)v * 128 + 64 + lane];
    volatile float* sm = smAtt[wIdx];
    const bool fits = (len <= CAP);
    float m = -3.4e38f, ssum = 0.f, acc0 = 0.f, acc1 = 0.f;
    for (int p = 0; p < len; ++p) {
        int s = esrc[b + p];
        int r = etyp[b + p];
        const float* h = ent + (size_t)s * 128;
        float re_h = h[lane], im_h = h[64 + lane];
        float2 cs = ctab[r * 64 + lane];
        float re_s = re_h * cs.x - im_h * cs.y - re_t;
        float im_s = re_h * cs.y + im_h * cs.x - im_t;
        float a = sqrtf(re_s * re_s + im_s * im_s);
#pragma unroll
        for (int o = 32; o; o >>= 1) a += __shfl_xor(a, o);  // butterfly: all lanes hold total
        if (lane == 0) {
            if (fits) sm[p] = a;
            else ews[b + p] = a;  // raw score parking (fallback)
        }
        if (a > m) {  // wave-uniform branch (a uniform after butterfly)
            float corr = __expf(m - a);
            ssum *= corr;
            acc0 *= corr;
            acc1 *= corr;
            m = a;
        }
        float e = __expf(a - m);
        ssum += e;
        acc0 += e * re_h;
        acc1 += e * im_h;
    }
    float inv = 1.f / ssum;
    side[(size_t)v * 128 + lane] = acc0 * inv;
    side[(size_t)v * 128 + 64 + lane] = acc1 * inv;
    if (fits) {
        for (int p = lane; p < len; p += 64) ews[b + p] = __expf(sm[p] - m) * inv;
    } else {
        __threadfence();
        for (int p = lane; p < len; p += 64) ews[b + p] = __expf(ews[b + p] - m) * inv;
    }
}

// ---------------- side = segment_sum(ews * ego[src]) for layers 1,2: one wave per node ----------------
template <int DIN>
__global__ __launch_bounds__(256) void side_kernel(const float* __restrict__ ego, const float* __restrict__ ews,
                                                   const int* __restrict__ esrc, const int* __restrict__ offs,
                                                   float* __restrict__ side, int n) {
    int gid = blockIdx.x * blockDim.x + threadIdx.x;
    int wid = gid >> 6, lane = gid & 63;
    if (wid >= n) return;
    int v = wid;
    float acc = 0.f;
    int b = offs[v], e2 = offs[v + 1];
    for (int p = b; p < e2; ++p) {
        float w = ews[p];
        int s = esrc[p];
        if (lane < DIN) acc += w * ego[(size_t)s * DIN + lane];
    }
    if (lane < DIN) side[(size_t)v * DIN + lane] = acc;
}

// ---------------- fused layer: weights-stationary (VGPR) wave-pair design ----------------
// Lane j owns output column j (j = lane & (DOUT-1)). Even wave of a pair computes
// lrelu((e+s)@W1+b1), odd wave lrelu((e*s)@W2+b2) for the same node; combined via a
// tiny LDS exchange. Row broadcast via v_readlane (pure VALU, no LDS pipe). Next
// node's e,s prefetched during the FMA loop. No 64KB LDS -> ~3 waves/SIMD occupancy.
template <int DIN, int DOUT>
__global__ __launch_bounds__(256) void layer_kernel(const float* __restrict__ ego, const float* __restrict__ side,
                                                    const float* __restrict__ W1, const float* __restrict__ b1,
                                                    const float* __restrict__ W2, const float* __restrict__ b2,
                                                    float* __restrict__ ego_next, float* __restrict__ out,
                                                    int colOff, int n) {
    __shared__ float cross[2][64];
    const int lane = threadIdx.x & 63;
    const int wid = threadIdx.x >> 6;
    const int slotIdx = wid >> 1;  // node slot within block: 0,1
    const int role = wid & 1;      // 0 -> (e+s)@W1, 1 -> (e*s)@W2
    const int jj = lane & (DOUT - 1);
    const float* W = role ? W2 : W1;
    const float bias = (role ? b2 : b1)[jj];
    // stationary weight column in VGPRs
    float w[DIN];
#pragma unroll
    for (int k = 0; k < DIN; ++k) w[k] = W[k * DOUT + jj];
    constexpr int SLOTS = (DIN + 63) / 64;
    const int dim0 = (DIN >= 64) ? lane : (lane & (DIN - 1));
    const int stride = gridDim.x * 2;
    int v = blockIdx.x * 2 + slotIdx;
    const int nIter = (n + stride - 1) / stride;
    float ce[SLOTS], cs[SLOTS], ne[SLOTS], ns[SLOTS];
#pragma unroll
    for (int k = 0; k < SLOTS; ++k) { ce[k] = 0.f; cs[k] = 0.f; ne[k] = 0.f; ns[k] = 0.f; }
    if (v < n) {
#pragma unroll
        for (int k = 0; k < SLOTS; ++k) {
            ce[k] = ego[(size_t)v * DIN + k * 64 + dim0];
            cs[k] = side[(size_t)v * DIN + k * 64 + dim0];
        }
    }
    for (int it = 0; it < nIter; ++it) {
        int nv = v + stride;
        if (it + 1 < nIter && nv < n) {
#pragma unroll
            for (int k = 0; k < SLOTS; ++k) {
                ne[k] = ego[(size_t)nv * DIN + k * 64 + dim0];
                ns[k] = side[(size_t)nv * DIN + k * 64 + dim0];
            }
        }
        float x[SLOTS];
#pragma unroll
        for (int k = 0; k < SLOTS; ++k) x[k] = role ? ce[k] * cs[k] : ce[k] + cs[k];
        float acc = bias;
#pragma unroll
        for (int i = 0; i < DIN; ++i) {
            float xv = __uint_as_float(__builtin_amdgcn_readlane(__float_as_uint(x[i >> 6]), i & 63));
            acc = fmaf(xv, w[i], acc);
        }
        acc = lrelu(acc);
        if (role == 1) cross[slotIdx][lane] = acc;
        __syncthreads();
        if (role == 0 && v < n) {  // wave-uniform guard
            float eg = acc + cross[slotIdx][jj];
            float sq = (lane < DOUT) ? eg * eg : 0.f;
#pragma unroll
            for (int o = 32; o; o >>= 1) sq += __shfl_xor(sq, o);
            float inv = 1.f / fmaxf(sqrtf(sq), 1e-12f);
            if (lane < DOUT) {
                ego_next[(size_t)v * DOUT + lane] = eg;
                out[(size_t)v * OUTW + colOff + lane] = eg * inv;
            }
        }
        __syncthreads();
        v = nv;
#pragma unroll
        for (int k = 0; k < SLOTS; ++k) { ce[k] = ne[k]; cs[k] = ns[k]; }
    }
}

// ---------------- copy ent_embed into out[:, 0:128] ----------------
__global__ __launch_bounds__(256) void copy_ent(const float4* __restrict__ ent4, float* __restrict__ out, int n) {
    int idx = blockIdx.x * blockDim.x + threadIdx.x;
    int total = n * 32;  // 128 floats = 32 float4 per row
    if (idx >= total) return;
    int v = idx >> 5, c = idx & 31;
    float4 x = ent4[idx];
    *(float4*)(out + (size_t)v * OUTW + c * 4) = x;
}

extern "C" void kernel_launch(void* const* d_in, const int* in_sizes, int n_in,
                              void* d_out, int out_size, void* d_ws, size_t ws_size,
                              hipStream_t stream) {
    const float* ent = (const float*)d_in[0];
    const float* rel = (const float*)d_in[1];
    const float* W1_0 = (const float*)d_in[2];
    const float* b1_0 = (const float*)d_in[3];
    const float* W2_0 = (const float*)d_in[4];
    const float* b2_0 = (const float*)d_in[5];
    const float* W1_1 = (const float*)d_in[6];
    const float* b1_1 = (const float*)d_in[7];
    const float* W2_1 = (const float*)d_in[8];
    const float* b2_1 = (const float*)d_in[9];
    const float* W1_2 = (const float*)d_in[10];
    const float* b1_2 = (const float*)d_in[11];
    const float* W2_2 = (const float*)d_in[12];
    const float* b2_2 = (const float*)d_in[13];
    const int* esrc_in = (const int*)d_in[14];
    const int* edst_in = (const int*)d_in[15];
    const int* etyp_in = (const int*)d_in[16];
    float* out = (float*)d_out;

    const int N = in_sizes[0] / 128;
    const int E = in_sizes[14];
    const int RD = in_sizes[1];  // R*64

    // ---- carve workspace ----
    char* p = (char*)d_ws;
    auto alloc = [&](size_t bytes) -> void* {
        void* r = (void*)p;
        p += (bytes + 255) & ~(size_t)255;
        return r;
    };
    float2* ctab = (float2*)alloc((size_t)RD * 8);
    float* ews = (float*)alloc((size_t)E * 4);
    int* esrc = (int*)alloc((size_t)E * 4);
    int* etyp = (int*)alloc((size_t)E * 4);
    int* deg = (int*)alloc((size_t)N * 4);
    int* cur = (int*)alloc((size_t)N * 4);
    int* incl = (int*)alloc((size_t)N * 4);
    int* offs = (int*)alloc((size_t)(N + 1) * 4);
    int* bsum = (int*)alloc(512);
    int* bbase = (int*)alloc(512);
    float* side = (float*)alloc((size_t)N * 128 * 4);
    float* ego1 = (float*)alloc((size_t)N * 64 * 4);
    float* ego2 = (float*)alloc((size_t)N * 32 * 4);
    float* ego3 = (float*)alloc((size_t)N * 16 * 4);

    // ---- zero atomic counters (ws is poisoned each launch) ----
    hipMemsetAsync(deg, 0, (size_t)N * 4, stream);
    hipMemsetAsync(cur, 0, (size_t)N * 4, stream);

    // ---- cos/sin table ----
    cossin_kernel<<<(RD + 255) / 256, 256, 0, stream>>>(rel, ctab, RD);

    // ---- CSR build ----
    hist_kernel<<<(E + 255) / 256, 256, 0, stream>>>(edst_in, deg, E);
    int nb1 = (N + 1023) / 1024;
    scan_partial<<<nb1, 1024, 0, stream>>>(deg, incl, bsum, N);
    scan_bsums<<<1, 128, 0, stream>>>(bsum, bbase, nb1);
    scan_final<<<nb1, 1024, 0, stream>>>(incl, bbase, offs, N);
    fill_kernel<<<(E + 255) / 256, 256, 0, stream>>>(esrc_in, edst_in, etyp_in, offs, cur, esrc, etyp, E);

    // ---- fused attention + softmax + layer-0 side (single gather pass) ----
    fused_att_kernel<<<(N + 3) / 4, 256, 0, stream>>>(ent, ctab, offs, esrc, etyp, ews, side, N);

    // ---- layer 0: din=128, dout=64 ----
    layer_kernel<128, 64><<<768, 256, 0, stream>>>(ent, side, W1_0, b1_0, W2_0, b2_0, ego1, out, 128, N);

    // ---- layer 1: din=64, dout=32 ----
    side_kernel<64><<<(N + 3) / 4, 256, 0, stream>>>(ego1, ews, esrc, offs, side, N);
    layer_kernel<64, 32><<<768, 256, 0, stream>>>(ego1, side, W1_1, b1_1, W2_1, b2_1, ego2, out, 192, N);

    // ---- layer 2: din=32, dout=16 ----
    side_kernel<32><<<(N + 3) / 4, 256, 0, stream>>>(ego2, ews, esrc, offs, side, N);
    layer_kernel<32, 16><<<768, 256, 0, stream>>>(ego2, side, W1_2, b1_2, W2_2, b2_2, ego3, out, 224, N);

    // ---- out[:, 0:128] = ent_embed ----
    copy_ent<<<((N * 32) + 255) / 256, 256, 0, stream>>>((const float4*)ent, out, N);
}

// Round 4
// 838.256 us; speedup vs baseline: 1.7371x; 1.2058x over previous
//
#include <hip/hip_runtime.h>
#include <hip/hip_bf16.h>
#include <math.h>
#include <stdint.h>

#define OUTW 240  // 128 + 64 + 32 + 16
#define CAP 1024  // per-wave LDS att buffer (max degree supported on fast path)

__device__ __forceinline__ float lrelu(float x) { return x > 0.f ? x : 0.01f * x; }

// ---------------- cos/sin tables (separate, for float4 loads): R*64 entries ----------------
__global__ __launch_bounds__(256) void cossin_kernel(const float* __restrict__ rel,
                                                     float* __restrict__ cost,
                                                     float* __restrict__ sint, int n) {
    int i = blockIdx.x * blockDim.x + threadIdx.x;
    if (i >= n) return;
    const float PHASE_SCALE = (float)(3.1415926235897933 / ((12.0 + 2.0) / 64.0));
    float p = rel[i] * PHASE_SCALE;
    cost[i] = cosf(p);
    sint[i] = sinf(p);
}

// ---------------- histogram of dst ----------------
__global__ __launch_bounds__(256) void hist_kernel(const int* __restrict__ dst, int* __restrict__ deg, int E) {
    int e = blockIdx.x * blockDim.x + threadIdx.x;
    if (e >= E) return;
    atomicAdd(&deg[dst[e]], 1);
}

// ---------------- 3-kernel exclusive scan over N (offsets) ----------------
__global__ __launch_bounds__(1024) void scan_partial(const int* __restrict__ deg, int* __restrict__ incl,
                                                     int* __restrict__ bsum, int n) {
    __shared__ int sm[1024];
    int i = blockIdx.x * 1024 + threadIdx.x;
    int x = (i < n) ? deg[i] : 0;
    sm[threadIdx.x] = x;
    __syncthreads();
    for (int off = 1; off < 1024; off <<= 1) {
        int y = (threadIdx.x >= off) ? sm[threadIdx.x - off] : 0;
        __syncthreads();
        sm[threadIdx.x] += y;
        __syncthreads();
    }
    if (i < n) incl[i] = sm[threadIdx.x];
    if (threadIdx.x == 1023) bsum[blockIdx.x] = sm[1023];
}

__global__ __launch_bounds__(128) void scan_bsums(const int* __restrict__ bsum, int* __restrict__ bbase, int nb) {
    __shared__ int sm[128];
    int t = threadIdx.x;
    int x = (t < nb) ? bsum[t] : 0;
    sm[t] = x;
    __syncthreads();
    for (int off = 1; off < 128; off <<= 1) {
        int y = (t >= off) ? sm[t - off] : 0;
        __syncthreads();
        sm[t] += y;
        __syncthreads();
    }
    if (t < nb) bbase[t] = sm[t] - x;  // exclusive
}

__global__ __launch_bounds__(1024) void scan_final(const int* __restrict__ incl, const int* __restrict__ bbase,
                                                   int* __restrict__ offs, int n) {
    int i = blockIdx.x * 1024 + threadIdx.x;
    if (i < n) offs[i + 1] = incl[i] + bbase[blockIdx.x];
    if (i == 0) offs[0] = 0;
}

// ---------------- CSR fill: src + type in CSR-by-dst order ----------------
__global__ __launch_bounds__(256) void fill_kernel(const int* __restrict__ src, const int* __restrict__ dst,
                                                   const int* __restrict__ typ, const int* __restrict__ offs,
                                                   int* __restrict__ cur, int* __restrict__ esrc,
                                                   int* __restrict__ etyp, int E) {
    int e = blockIdx.x * blockDim.x + threadIdx.x;
    if (e >= E) return;
    int d = dst[e];
    int pos = offs[d] + atomicAdd(&cur[d], 1);
    esrc[pos] = src[e];
    etyp[pos] = typ[e];
}

// ---------------- fused: RotatE att + edge softmax + layer-0 side ----------------
// One wave per node; 4 edges in flight per iteration (16 lanes x float4 per edge).
// Per-group online softmax (m, ssum, acc), merged across groups at the end.
__global__ __launch_bounds__(256) void fused_att_kernel(const float* __restrict__ ent,
                                                        const float* __restrict__ cost,
                                                        const float* __restrict__ sint,
                                                        const int* __restrict__ offs,
                                                        const int* __restrict__ esrc,
                                                        const int* __restrict__ etyp,
                                                        float* __restrict__ ews,
                                                        float* __restrict__ side, int n) {
    __shared__ float smAtt[4][CAP];
    const int wIdx = threadIdx.x >> 6, lane = threadIdx.x & 63;
    const int g = lane >> 4;   // edge slot 0..3
    const int l = lane & 15;   // dims 4l..4l+3
    int v = blockIdx.x * 4 + wIdx;
    if (v >= n) return;
    int b = offs[v];
    int len = offs[v + 1] - b;
    if (len == 0) {  // side must still be zero (ws is poisoned)
        side[(size_t)v * 128 + lane] = 0.f;
        side[(size_t)v * 128 + 64 + lane] = 0.f;
        return;
    }
    const float4* trow = (const float4*)(ent + (size_t)v * 128);
    float4 re_t = trow[l], im_t = trow[16 + l];
    volatile float* sm = smAtt[wIdx];
    const bool fits = (len <= CAP);
    float m = -3.4e38f, ssum = 0.f;
    float4 ar = {0.f, 0.f, 0.f, 0.f}, ai = {0.f, 0.f, 0.f, 0.f};
    for (int p0 = 0; p0 < len; p0 += 4) {
        int p = p0 + g;
        bool active = (p < len);
        int idx = b + (active ? p : 0);
        int s = esrc[idx];
        int r = etyp[idx];
        const float4* h = (const float4*)(ent + (size_t)s * 128);
        float4 re_h = h[l], im_h = h[16 + l];
        float4 c = ((const float4*)(cost + r * 64))[l];
        float4 si = ((const float4*)(sint + r * 64))[l];
        float rsx = re_h.x * c.x - im_h.x * si.x - re_t.x;
        float rsy = re_h.y * c.y - im_h.y * si.y - re_t.y;
        float rsz = re_h.z * c.z - im_h.z * si.z - re_t.z;
        float rsw = re_h.w * c.w - im_h.w * si.w - re_t.w;
        float isx = re_h.x * si.x + im_h.x * c.x - im_t.x;
        float isy = re_h.y * si.y + im_h.y * c.y - im_t.y;
        float isz = re_h.z * si.z + im_h.z * c.z - im_t.z;
        float isw = re_h.w * si.w + im_h.w * c.w - im_t.w;
        float a = sqrtf(rsx * rsx + isx * isx) + sqrtf(rsy * rsy + isy * isy) +
                  sqrtf(rsz * rsz + isz * isz) + sqrtf(rsw * rsw + isw * isw);
#pragma unroll
        for (int o = 8; o; o >>= 1) a += __shfl_xor(a, o);  // group-wide total
        if (!active) a = -3.4e38f;
        if (active && l == 0) {
            if (fits) sm[p] = a;
            else ews[b + p] = a;  // raw score parking (fallback)
        }
        if (a > m) {  // group-uniform branch
            float corr = __expf(m - a);
            ssum *= corr;
            ar.x *= corr; ar.y *= corr; ar.z *= corr; ar.w *= corr;
            ai.x *= corr; ai.y *= corr; ai.z *= corr; ai.w *= corr;
            m = a;
        }
        float e = __expf(a - m);  // inactive: a==-3.4e38 -> e==0 (or group fully inactive: e==1, zeroed in merge)
        ssum += e;
        ar.x += e * re_h.x; ar.y += e * re_h.y; ar.z += e * re_h.z; ar.w += e * re_h.w;
        ai.x += e * im_h.x; ai.y += e * im_h.y; ai.z += e * im_h.z; ai.w += e * im_h.w;
    }
    // ---- merge the 4 groups (scores >= 0, so real M > -3.4e38 and dead groups scale to 0) ----
    float M = m;
    M = fmaxf(M, __shfl_xor(M, 16));
    M = fmaxf(M, __shfl_xor(M, 32));
    float scale = __expf(m - M);
    float sg = ssum * scale;
    sg += __shfl_xor(sg, 16);
    sg += __shfl_xor(sg, 32);
    ar.x *= scale; ar.y *= scale; ar.z *= scale; ar.w *= scale;
    ai.x *= scale; ai.y *= scale; ai.z *= scale; ai.w *= scale;
#pragma unroll
    for (int o = 16; o <= 32; o <<= 1) {
        ar.x += __shfl_xor(ar.x, o); ar.y += __shfl_xor(ar.y, o);
        ar.z += __shfl_xor(ar.z, o); ar.w += __shfl_xor(ar.w, o);
        ai.x += __shfl_xor(ai.x, o); ai.y += __shfl_xor(ai.y, o);
        ai.z += __shfl_xor(ai.z, o); ai.w += __shfl_xor(ai.w, o);
    }
    float inv = 1.f / sg;
    if (g == 0) {
        float4* srow = (float4*)(side + (size_t)v * 128);
        float4 o0 = {ar.x * inv, ar.y * inv, ar.z * inv, ar.w * inv};
        float4 o1 = {ai.x * inv, ai.y * inv, ai.z * inv, ai.w * inv};
        srow[l] = o0;
        srow[16 + l] = o1;
    }
    if (fits) {
        for (int p = lane; p < len; p += 64) ews[b + p] = __expf(sm[p] - M) * inv;
    } else {
        __threadfence();
        for (int p = lane; p < len; p += 64) ews[b + p] = __expf(ews[b + p] - M) * inv;
    }
}

// ---------------- side for layer 1 (DIN=64): 4 edges in flight, float4 ----------------
__global__ __launch_bounds__(256) void side64_kernel(const float* __restrict__ ego, const float* __restrict__ ews,
                                                     const int* __restrict__ esrc, const int* __restrict__ offs,
                                                     float* __restrict__ side, int n) {
    const int wIdx = threadIdx.x >> 6, lane = threadIdx.x & 63;
    const int g = lane >> 4, l = lane & 15;  // dims 4l..4l+3
    int v = blockIdx.x * 4 + wIdx;
    if (v >= n) return;
    int b = offs[v], len = offs[v + 1] - b;
    float4 acc = {0.f, 0.f, 0.f, 0.f};
    for (int p0 = 0; p0 < len; p0 += 4) {
        int p = p0 + g;
        bool active = (p < len);
        int idx = b + (active ? p : 0);
        float w = active ? ews[idx] : 0.f;
        int s = esrc[idx];
        float4 eg = ((const float4*)(ego + (size_t)s * 64))[l];
        acc.x += w * eg.x; acc.y += w * eg.y; acc.z += w * eg.z; acc.w += w * eg.w;
    }
#pragma unroll
    for (int o = 16; o <= 32; o <<= 1) {
        acc.x += __shfl_xor(acc.x, o); acc.y += __shfl_xor(acc.y, o);
        acc.z += __shfl_xor(acc.z, o); acc.w += __shfl_xor(acc.w, o);
    }
    if (g == 0) ((float4*)(side + (size_t)v * 64))[l] = acc;
}

// ---------------- side for layer 2 (DIN=32): 4 edges in flight, float2 ----------------
__global__ __launch_bounds__(256) void side32_kernel(const float* __restrict__ ego, const float* __restrict__ ews,
                                                     const int* __restrict__ esrc, const int* __restrict__ offs,
                                                     float* __restrict__ side, int n) {
    const int wIdx = threadIdx.x >> 6, lane = threadIdx.x & 63;
    const int g = lane >> 4, l = lane & 15;  // dims 2l, 2l+1
    int v = blockIdx.x * 4 + wIdx;
    if (v >= n) return;
    int b = offs[v], len = offs[v + 1] - b;
    float2 acc = {0.f, 0.f};
    for (int p0 = 0; p0 < len; p0 += 4) {
        int p = p0 + g;
        bool active = (p < len);
        int idx = b + (active ? p : 0);
        float w = active ? ews[idx] : 0.f;
        int s = esrc[idx];
        float2 eg = ((const float2*)(ego + (size_t)s * 32))[l];
        acc.x += w * eg.x; acc.y += w * eg.y;
    }
#pragma unroll
    for (int o = 16; o <= 32; o <<= 1) {
        acc.x += __shfl_xor(acc.x, o);
        acc.y += __shfl_xor(acc.y, o);
    }
    if (g == 0) ((float2*)(side + (size_t)v * 32))[l] = acc;
}

// ---------------- fused layer: weights-stationary (VGPR) wave-pair design ----------------
template <int DIN, int DOUT>
__global__ __launch_bounds__(256) void layer_kernel(const float* __restrict__ ego, const float* __restrict__ side,
                                                    const float* __restrict__ W1, const float* __restrict__ b1,
                                                    const float* __restrict__ W2, const float* __restrict__ b2,
                                                    float* __restrict__ ego_next, float* __restrict__ out,
                                                    int colOff, int n) {
    __shared__ float cross[2][64];
    const int lane = threadIdx.x & 63;
    const int wid = threadIdx.x >> 6;
    const int slotIdx = wid >> 1;  // node slot within block: 0,1
    const int role = wid & 1;      // 0 -> (e+s)@W1, 1 -> (e*s)@W2
    const int jj = lane & (DOUT - 1);
    const float* W = role ? W2 : W1;
    const float bias = (role ? b2 : b1)[jj];
    float w[DIN];
#pragma unroll
    for (int k = 0; k < DIN; ++k) w[k] = W[k * DOUT + jj];
    constexpr int SLOTS = (DIN + 63) / 64;
    const int dim0 = (DIN >= 64) ? lane : (lane & (DIN - 1));
    const int stride = gridDim.x * 2;
    int v = blockIdx.x * 2 + slotIdx;
    const int nIter = (n + stride - 1) / stride;
    float ce[SLOTS], cs[SLOTS], ne[SLOTS], ns[SLOTS];
#pragma unroll
    for (int k = 0; k < SLOTS; ++k) { ce[k] = 0.f; cs[k] = 0.f; ne[k] = 0.f; ns[k] = 0.f; }
    if (v < n) {
#pragma unroll
        for (int k = 0; k < SLOTS; ++k) {
            ce[k] = ego[(size_t)v * DIN + k * 64 + dim0];
            cs[k] = side[(size_t)v * DIN + k * 64 + dim0];
        }
    }
    for (int it = 0; it < nIter; ++it) {
        int nv = v + stride;
        if (it + 1 < nIter && nv < n) {
#pragma unroll
            for (int k = 0; k < SLOTS; ++k) {
                ne[k] = ego[(size_t)nv * DIN + k * 64 + dim0];
                ns[k] = side[(size_t)nv * DIN + k * 64 + dim0];
            }
        }
        float x[SLOTS];
#pragma unroll
        for (int k = 0; k < SLOTS; ++k) x[k] = role ? ce[k] * cs[k] : ce[k] + cs[k];
        float acc = bias;
#pragma unroll
        for (int i = 0; i < DIN; ++i) {
            float xv = __uint_as_float(__builtin_amdgcn_readlane(__float_as_uint(x[i >> 6]), i & 63));
            acc = fmaf(xv, w[i], acc);
        }
        acc = lrelu(acc);
        if (role == 1) cross[slotIdx][lane] = acc;
        __syncthreads();
        if (role == 0 && v < n) {  // wave-uniform guard
            float eg = acc + cross[slotIdx][jj];
            float sq = (lane < DOUT) ? eg * eg : 0.f;
#pragma unroll
            for (int o = 32; o; o >>= 1) sq += __shfl_xor(sq, o);
            float inv = 1.f / fmaxf(sqrtf(sq), 1e-12f);
            if (lane < DOUT) {
                ego_next[(size_t)v * DOUT + lane] = eg;
                out[(size_t)v * OUTW + colOff + lane] = eg * inv;
            }
        }
        __syncthreads();
        v = nv;
#pragma unroll
        for (int k = 0; k < SLOTS; ++k) { ce[k] = ne[k]; cs[k] = ns[k]; }
    }
}

// ---------------- copy ent_embed into out[:, 0:128] ----------------
__global__ __launch_bounds__(256) void copy_ent(const float4* __restrict__ ent4, float* __restrict__ out, int n) {
    int idx = blockIdx.x * blockDim.x + threadIdx.x;
    int total = n * 32;  // 128 floats = 32 float4 per row
    if (idx >= total) return;
    int v = idx >> 5, c = idx & 31;
    float4 x = ent4[idx];
    *(float4*)(out + (size_t)v * OUTW + c * 4) = x;
}

extern "C" void kernel_launch(void* const* d_in, const int* in_sizes, int n_in,
                              void* d_out, int out_size, void* d_ws, size_t ws_size,
                              hipStream_t stream) {
    const float* ent = (const float*)d_in[0];
    const float* rel = (const float*)d_in[1];
    const float* W1_0 = (const float*)d_in[2];
    const float* b1_0 = (const float*)d_in[3];
    const float* W2_0 = (const float*)d_in[4];
    const float* b2_0 = (const float*)d_in[5];
    const float* W1_1 = (const float*)d_in[6];
    const float* b1_1 = (const float*)d_in[7];
    const float* W2_1 = (const float*)d_in[8];
    const float* b2_1 = (const float*)d_in[9];
    const float* W1_2 = (const float*)d_in[10];
    const float* b1_2 = (const float*)d_in[11];
    const float* W2_2 = (const float*)d_in[12];
    const float* b2_2 = (const float*)d_in[13];
    const int* esrc_in = (const int*)d_in[14];
    const int* edst_in = (const int*)d_in[15];
    const int* etyp_in = (const int*)d_in[16];
    float* out = (float*)d_out;

    const int N = in_sizes[0] / 128;
    const int E = in_sizes[14];
    const int RD = in_sizes[1];  // R*64

    // ---- carve workspace ----
    char* p = (char*)d_ws;
    auto alloc = [&](size_t bytes) -> void* {
        void* r = (void*)p;
        p += (bytes + 255) & ~(size_t)255;
        return r;
    };
    float* cost = (float*)alloc((size_t)RD * 4);
    float* sint = (float*)alloc((size_t)RD * 4);
    float* ews = (float*)alloc((size_t)E * 4);
    int* esrc = (int*)alloc((size_t)E * 4);
    int* etyp = (int*)alloc((size_t)E * 4);
    int* deg = (int*)alloc((size_t)N * 4);
    int* cur = (int*)alloc((size_t)N * 4);
    int* incl = (int*)alloc((size_t)N * 4);
    int* offs = (int*)alloc((size_t)(N + 1) * 4);
    int* bsum = (int*)alloc(512);
    int* bbase = (int*)alloc(512);
    float* side = (float*)alloc((size_t)N * 128 * 4);
    float* ego1 = (float*)alloc((size_t)N * 64 * 4);
    float* ego2 = (float*)alloc((size_t)N * 32 * 4);
    float* ego3 = (float*)alloc((size_t)N * 16 * 4);

    // ---- zero atomic counters (ws is poisoned each launch) ----
    hipMemsetAsync(deg, 0, (size_t)N * 4, stream);
    hipMemsetAsync(cur, 0, (size_t)N * 4, stream);

    // ---- cos/sin tables ----
    cossin_kernel<<<(RD + 255) / 256, 256, 0, stream>>>(rel, cost, sint, RD);

    // ---- CSR build ----
    hist_kernel<<<(E + 255) / 256, 256, 0, stream>>>(edst_in, deg, E);
    int nb1 = (N + 1023) / 1024;
    scan_partial<<<nb1, 1024, 0, stream>>>(deg, incl, bsum, N);
    scan_bsums<<<1, 128, 0, stream>>>(bsum, bbase, nb1);
    scan_final<<<nb1, 1024, 0, stream>>>(incl, bbase, offs, N);
    fill_kernel<<<(E + 255) / 256, 256, 0, stream>>>(esrc_in, edst_in, etyp_in, offs, cur, esrc, etyp, E);

    // ---- fused attention + softmax + layer-0 side (single gather pass) ----
    fused_att_kernel<<<(N + 3) / 4, 256, 0, stream>>>(ent, cost, sint, offs, esrc, etyp, ews, side, N);

    // ---- layer 0: din=128, dout=64 ----
    layer_kernel<128, 64><<<768, 256, 0, stream>>>(ent, side, W1_0, b1_0, W2_0, b2_0, ego1, out, 128, N);

    // ---- layer 1: din=64, dout=32 ----
    side64_kernel<<<(N + 3) / 4, 256, 0, stream>>>(ego1, ews, esrc, offs, side, N);
    layer_kernel<64, 32><<<768, 256, 0, stream>>>(ego1, side, W1_1, b1_1, W2_1, b2_1, ego2, out, 192, N);

    // ---- layer 2: din=32, dout=16 ----
    side32_kernel<<<(N + 3) / 4, 256, 0, stream>>>(ego2, ews, esrc, offs, side, N);
    layer_kernel<32, 16><<<768, 256, 0, stream>>>(ego2, side, W1_2, b1_2, W2_2, b2_2, ego3, out, 224, N);

    // ---- out[:, 0:128] = ent_embed ----
    copy_ent<<<((N * 32) + 255) / 256, 256, 0, stream>>>((const float4*)ent, out, N);
}

// Round 6
// 720.091 us; speedup vs baseline: 2.0221x; 1.1641x over previous
//
#include <hip/hip_runtime.h>
#include <hip/hip_bf16.h>
#include <math.h>
#include <stdint.h>

#define OUTW 240  // 128 + 64 + 32 + 16
#define CAP 1024  // per-wave LDS att buffer (max degree supported on fast path)

__device__ __forceinline__ float lrelu(float x) { return x > 0.f ? x : 0.01f * x; }

// ---------------- cos/sin tables (separate, for float4 loads): R*64 entries ----------------
__global__ __launch_bounds__(256) void cossin_kernel(const float* __restrict__ rel,
                                                     float* __restrict__ cost,
                                                     float* __restrict__ sint, int n) {
    int i = blockIdx.x * blockDim.x + threadIdx.x;
    if (i >= n) return;
    const float PHASE_SCALE = (float)(3.1415926235897933 / ((12.0 + 2.0) / 64.0));
    float p = rel[i] * PHASE_SCALE;
    cost[i] = cosf(p);
    sint[i] = sinf(p);
}

// ---------------- histogram of dst ----------------
__global__ __launch_bounds__(256) void hist_kernel(const int* __restrict__ dst, int* __restrict__ deg, int E) {
    int e = blockIdx.x * blockDim.x + threadIdx.x;
    if (e >= E) return;
    atomicAdd(&deg[dst[e]], 1);
}

// ---------------- 3-kernel exclusive scan over N (offsets) ----------------
__global__ __launch_bounds__(1024) void scan_partial(const int* __restrict__ deg, int* __restrict__ incl,
                                                     int* __restrict__ bsum, int n) {
    __shared__ int sm[1024];
    int i = blockIdx.x * 1024 + threadIdx.x;
    int x = (i < n) ? deg[i] : 0;
    sm[threadIdx.x] = x;
    __syncthreads();
    for (int off = 1; off < 1024; off <<= 1) {
        int y = (threadIdx.x >= off) ? sm[threadIdx.x - off] : 0;
        __syncthreads();
        sm[threadIdx.x] += y;
        __syncthreads();
    }
    if (i < n) incl[i] = sm[threadIdx.x];
    if (threadIdx.x == 1023) bsum[blockIdx.x] = sm[1023];
}

__global__ __launch_bounds__(128) void scan_bsums(const int* __restrict__ bsum, int* __restrict__ bbase, int nb) {
    __shared__ int sm[128];
    int t = threadIdx.x;
    int x = (t < nb) ? bsum[t] : 0;
    sm[t] = x;
    __syncthreads();
    for (int off = 1; off < 128; off <<= 1) {
        int y = (t >= off) ? sm[t - off] : 0;
        __syncthreads();
        sm[t] += y;
        __syncthreads();
    }
    if (t < nb) bbase[t] = sm[t] - x;  // exclusive
}

__global__ __launch_bounds__(1024) void scan_final(const int* __restrict__ incl, const int* __restrict__ bbase,
                                                   int* __restrict__ offs, int n) {
    int i = blockIdx.x * 1024 + threadIdx.x;
    if (i < n) offs[i + 1] = incl[i] + bbase[blockIdx.x];
    if (i == 0) offs[0] = 0;
}

// ---------------- CSR fill: src + type in CSR-by-dst order ----------------
__global__ __launch_bounds__(256) void fill_kernel(const int* __restrict__ src, const int* __restrict__ dst,
                                                   const int* __restrict__ typ, const int* __restrict__ offs,
                                                   int* __restrict__ cur, int* __restrict__ esrc,
                                                   int* __restrict__ etyp, int E) {
    int e = blockIdx.x * blockDim.x + threadIdx.x;
    if (e >= E) return;
    int d = dst[e];
    int pos = offs[d] + atomicAdd(&cur[d], 1);
    esrc[pos] = src[e];
    etyp[pos] = typ[e];
}

// ---------------- fused: RotatE att + edge softmax + layer-0 side ----------------
__global__ __launch_bounds__(256) void fused_att_kernel(const float* __restrict__ ent,
                                                        const float* __restrict__ cost,
                                                        const float* __restrict__ sint,
                                                        const int* __restrict__ offs,
                                                        const int* __restrict__ esrc,
                                                        const int* __restrict__ etyp,
                                                        float* __restrict__ ews,
                                                        float* __restrict__ side, int n) {
    __shared__ float smAtt[4][CAP];
    const int wIdx = threadIdx.x >> 6, lane = threadIdx.x & 63;
    const int g = lane >> 4;   // edge slot 0..3
    const int l = lane & 15;   // dims 4l..4l+3
    int v = blockIdx.x * 4 + wIdx;
    if (v >= n) return;
    int b = offs[v];
    int len = offs[v + 1] - b;
    if (len == 0) {  // side must still be zero (ws is poisoned)
        side[(size_t)v * 128 + lane] = 0.f;
        side[(size_t)v * 128 + 64 + lane] = 0.f;
        return;
    }
    const float4* trow = (const float4*)(ent + (size_t)v * 128);
    float4 re_t = trow[l], im_t = trow[16 + l];
    volatile float* sm = smAtt[wIdx];
    const bool fits = (len <= CAP);
    float m = -3.4e38f, ssum = 0.f;
    float4 ar = {0.f, 0.f, 0.f, 0.f}, ai = {0.f, 0.f, 0.f, 0.f};
    for (int p0 = 0; p0 < len; p0 += 4) {
        int p = p0 + g;
        bool active = (p < len);
        int idx = b + (active ? p : 0);
        int s = esrc[idx];
        int r = etyp[idx];
        const float4* h = (const float4*)(ent + (size_t)s * 128);
        float4 re_h = h[l], im_h = h[16 + l];
        float4 c = ((const float4*)(cost + r * 64))[l];
        float4 si = ((const float4*)(sint + r * 64))[l];
        float rsx = re_h.x * c.x - im_h.x * si.x - re_t.x;
        float rsy = re_h.y * c.y - im_h.y * si.y - re_t.y;
        float rsz = re_h.z * c.z - im_h.z * si.z - re_t.z;
        float rsw = re_h.w * c.w - im_h.w * si.w - re_t.w;
        float isx = re_h.x * si.x + im_h.x * c.x - im_t.x;
        float isy = re_h.y * si.y + im_h.y * c.y - im_t.y;
        float isz = re_h.z * si.z + im_h.z * c.z - im_t.z;
        float isw = re_h.w * si.w + im_h.w * c.w - im_t.w;
        float a = sqrtf(rsx * rsx + isx * isx) + sqrtf(rsy * rsy + isy * isy) +
                  sqrtf(rsz * rsz + isz * isz) + sqrtf(rsw * rsw + isw * isw);
#pragma unroll
        for (int o = 8; o; o >>= 1) a += __shfl_xor(a, o);  // group-wide total
        if (!active) a = -3.4e38f;
        if (active && l == 0) {
            if (fits) sm[p] = a;
            else ews[b + p] = a;  // raw score parking (fallback)
        }
        if (a > m) {  // group-uniform branch
            float corr = __expf(m - a);
            ssum *= corr;
            ar.x *= corr; ar.y *= corr; ar.z *= corr; ar.w *= corr;
            ai.x *= corr; ai.y *= corr; ai.z *= corr; ai.w *= corr;
            m = a;
        }
        float e = __expf(a - m);  // inactive: a==-3.4e38 -> e==0 (or group fully inactive: e==1, zeroed in merge)
        ssum += e;
        ar.x += e * re_h.x; ar.y += e * re_h.y; ar.z += e * re_h.z; ar.w += e * re_h.w;
        ai.x += e * im_h.x; ai.y += e * im_h.y; ai.z += e * im_h.z; ai.w += e * im_h.w;
    }
    // ---- merge the 4 groups (scores >= 0, so real M > -3.4e38 and dead groups scale to 0) ----
    float M = m;
    M = fmaxf(M, __shfl_xor(M, 16));
    M = fmaxf(M, __shfl_xor(M, 32));
    float scale = __expf(m - M);
    float sg = ssum * scale;
    sg += __shfl_xor(sg, 16);
    sg += __shfl_xor(sg, 32);
    ar.x *= scale; ar.y *= scale; ar.z *= scale; ar.w *= scale;
    ai.x *= scale; ai.y *= scale; ai.z *= scale; ai.w *= scale;
#pragma unroll
    for (int o = 16; o <= 32; o <<= 1) {
        ar.x += __shfl_xor(ar.x, o); ar.y += __shfl_xor(ar.y, o);
        ar.z += __shfl_xor(ar.z, o); ar.w += __shfl_xor(ar.w, o);
        ai.x += __shfl_xor(ai.x, o); ai.y += __shfl_xor(ai.y, o);
        ai.z += __shfl_xor(ai.z, o); ai.w += __shfl_xor(ai.w, o);
    }
    float inv = 1.f / sg;
    if (g == 0) {
        float4* srow = (float4*)(side + (size_t)v * 128);
        float4 o0 = {ar.x * inv, ar.y * inv, ar.z * inv, ar.w * inv};
        float4 o1 = {ai.x * inv, ai.y * inv, ai.z * inv, ai.w * inv};
        srow[l] = o0;
        srow[16 + l] = o1;
    }
    if (fits) {
        for (int p = lane; p < len; p += 64) ews[b + p] = __expf(sm[p] - M) * inv;
    } else {
        __threadfence();
        for (int p = lane; p < len; p += 64) ews[b + p] = __expf(ews[b + p] - M) * inv;
    }
}

// ---------------- side for layer 1 (DIN=64): 4 edges in flight, float4 ----------------
__global__ __launch_bounds__(256) void side64_kernel(const float* __restrict__ ego, const float* __restrict__ ews,
                                                     const int* __restrict__ esrc, const int* __restrict__ offs,
                                                     float* __restrict__ side, int n) {
    const int wIdx = threadIdx.x >> 6, lane = threadIdx.x & 63;
    const int g = lane >> 4, l = lane & 15;  // dims 4l..4l+3
    int v = blockIdx.x * 4 + wIdx;
    if (v >= n) return;
    int b = offs[v], len = offs[v + 1] - b;
    float4 acc = {0.f, 0.f, 0.f, 0.f};
    for (int p0 = 0; p0 < len; p0 += 4) {
        int p = p0 + g;
        bool active = (p < len);
        int idx = b + (active ? p : 0);
        float w = active ? ews[idx] : 0.f;
        int s = esrc[idx];
        float4 eg = ((const float4*)(ego + (size_t)s * 64))[l];
        acc.x += w * eg.x; acc.y += w * eg.y; acc.z += w * eg.z; acc.w += w * eg.w;
    }
#pragma unroll
    for (int o = 16; o <= 32; o <<= 1) {
        acc.x += __shfl_xor(acc.x, o); acc.y += __shfl_xor(acc.y, o);
        acc.z += __shfl_xor(acc.z, o); acc.w += __shfl_xor(acc.w, o);
    }
    if (g == 0) ((float4*)(side + (size_t)v * 64))[l] = acc;
}

// ---------------- side for layer 2 (DIN=32): 4 edges in flight, float2 ----------------
__global__ __launch_bounds__(256) void side32_kernel(const float* __restrict__ ego, const float* __restrict__ ews,
                                                     const int* __restrict__ esrc, const int* __restrict__ offs,
                                                     float* __restrict__ side, int n) {
    const int wIdx = threadIdx.x >> 6, lane = threadIdx.x & 63;
    const int g = lane >> 4, l = lane & 15;  // dims 2l, 2l+1
    int v = blockIdx.x * 4 + wIdx;
    if (v >= n) return;
    int b = offs[v], len = offs[v + 1] - b;
    float2 acc = {0.f, 0.f};
    for (int p0 = 0; p0 < len; p0 += 4) {
        int p = p0 + g;
        bool active = (p < len);
        int idx = b + (active ? p : 0);
        float w = active ? ews[idx] : 0.f;
        int s = esrc[idx];
        float2 eg = ((const float2*)(ego + (size_t)s * 32))[l];
        acc.x += w * eg.x; acc.y += w * eg.y;
    }
#pragma unroll
    for (int o = 16; o <= 32; o <<= 1) {
        acc.x += __shfl_xor(acc.x, o);
        acc.y += __shfl_xor(acc.y, o);
    }
    if (g == 0) ((float2*)(side + (size_t)v * 32))[l] = acc;
}

// ---------------- fused layer: weights-stationary (VGPR) wave-pair design ----------------
// __launch_bounds__(256,1): free the register allocator so the w[DIN] column STAYS in
// VGPRs (round-3 build: VGPR_Count=80 < DIN -> compiler rematerialized weight loads in
// the FMA loop). 4 partial accumulators break the serial FMA dependency chain.
template <int DIN, int DOUT>
__global__ __launch_bounds__(256, 1) void layer_kernel(const float* __restrict__ ego, const float* __restrict__ side,
                                                       const float* __restrict__ W1, const float* __restrict__ b1,
                                                       const float* __restrict__ W2, const float* __restrict__ b2,
                                                       float* __restrict__ ego_next, float* __restrict__ out,
                                                       int colOff, int n) {
    __shared__ float cross[2][64];
    const int lane = threadIdx.x & 63;
    const int wid = threadIdx.x >> 6;
    const int slotIdx = wid >> 1;  // node slot within block: 0,1
    const int role = wid & 1;      // 0 -> (e+s)@W1, 1 -> (e*s)@W2
    const int jj = lane & (DOUT - 1);
    const float* W = role ? W2 : W1;
    const float bias = (role ? b2 : b1)[jj];
    float w[DIN];
#pragma unroll
    for (int k = 0; k < DIN; ++k) w[k] = W[k * DOUT + jj];
    constexpr int SLOTS = (DIN + 63) / 64;
    const int dim0 = (DIN >= 64) ? lane : (lane & (DIN - 1));
    const int stride = gridDim.x * 2;
    int v = blockIdx.x * 2 + slotIdx;
    const int nIter = (n + stride - 1) / stride;
    float ce[SLOTS], cs[SLOTS], ne[SLOTS], ns[SLOTS];
#pragma unroll
    for (int k = 0; k < SLOTS; ++k) { ce[k] = 0.f; cs[k] = 0.f; ne[k] = 0.f; ns[k] = 0.f; }
    if (v < n) {
#pragma unroll
        for (int k = 0; k < SLOTS; ++k) {
            ce[k] = ego[(size_t)v * DIN + k * 64 + dim0];
            cs[k] = side[(size_t)v * DIN + k * 64 + dim0];
        }
    }
    for (int it = 0; it < nIter; ++it) {
        int nv = v + stride;
        if (it + 1 < nIter && nv < n) {
#pragma unroll
            for (int k = 0; k < SLOTS; ++k) {
                ne[k] = ego[(size_t)nv * DIN + k * 64 + dim0];
                ns[k] = side[(size_t)nv * DIN + k * 64 + dim0];
            }
        }
        float x[SLOTS];
#pragma unroll
        for (int k = 0; k < SLOTS; ++k) x[k] = role ? ce[k] * cs[k] : ce[k] + cs[k];
        // 4 partial accumulators: break the serial FMA chain (ILP=4)
        float a0 = bias, a1 = 0.f, a2 = 0.f, a3 = 0.f;
#pragma unroll
        for (int i = 0; i < DIN; i += 4) {
            float xv0 = __uint_as_float(__builtin_amdgcn_readlane(__float_as_uint(x[(i + 0) >> 6]), (i + 0) & 63));
            float xv1 = __uint_as_float(__builtin_amdgcn_readlane(__float_as_uint(x[(i + 1) >> 6]), (i + 1) & 63));
            float xv2 = __uint_as_float(__builtin_amdgcn_readlane(__float_as_uint(x[(i + 2) >> 6]), (i + 2) & 63));
            float xv3 = __uint_as_float(__builtin_amdgcn_readlane(__float_as_uint(x[(i + 3) >> 6]), (i + 3) & 63));
            a0 = fmaf(xv0, w[i + 0], a0);
            a1 = fmaf(xv1, w[i + 1], a1);
            a2 = fmaf(xv2, w[i + 2], a2);
            a3 = fmaf(xv3, w[i + 3], a3);
        }
        float acc = (a0 + a1) + (a2 + a3);
        acc = lrelu(acc);
        if (role == 1) cross[slotIdx][lane] = acc;
        __syncthreads();
        if (role == 0 && v < n) {  // wave-uniform guard
            float eg = acc + cross[slotIdx][jj];
            float sq = (lane < DOUT) ? eg * eg : 0.f;
#pragma unroll
            for (int o = 32; o; o >>= 1) sq += __shfl_xor(sq, o);
            float inv = 1.f / fmaxf(sqrtf(sq), 1e-12f);
            if (lane < DOUT) {
                ego_next[(size_t)v * DOUT + lane] = eg;
                out[(size_t)v * OUTW + colOff + lane] = eg * inv;
            }
        }
        __syncthreads();
        v = nv;
#pragma unroll
        for (int k = 0; k < SLOTS; ++k) { ce[k] = ne[k]; cs[k] = ns[k]; }
    }
}

// ---------------- copy ent_embed into out[:, 0:128] ----------------
__global__ __launch_bounds__(256) void copy_ent(const float4* __restrict__ ent4, float* __restrict__ out, int n) {
    int idx = blockIdx.x * blockDim.x + threadIdx.x;
    int total = n * 32;  // 128 floats = 32 float4 per row
    if (idx >= total) return;
    int v = idx >> 5, c = idx & 31;
    float4 x = ent4[idx];
    *(float4*)(out + (size_t)v * OUTW + c * 4) = x;
}

extern "C" void kernel_launch(void* const* d_in, const int* in_sizes, int n_in,
                              void* d_out, int out_size, void* d_ws, size_t ws_size,
                              hipStream_t stream) {
    const float* ent = (const float*)d_in[0];
    const float* rel = (const float*)d_in[1];
    const float* W1_0 = (const float*)d_in[2];
    const float* b1_0 = (const float*)d_in[3];
    const float* W2_0 = (const float*)d_in[4];
    const float* b2_0 = (const float*)d_in[5];
    const float* W1_1 = (const float*)d_in[6];
    const float* b1_1 = (const float*)d_in[7];
    const float* W2_1 = (const float*)d_in[8];
    const float* b2_1 = (const float*)d_in[9];
    const float* W1_2 = (const float*)d_in[10];
    const float* b1_2 = (const float*)d_in[11];
    const float* W2_2 = (const float*)d_in[12];
    const float* b2_2 = (const float*)d_in[13];
    const int* esrc_in = (const int*)d_in[14];
    const int* edst_in = (const int*)d_in[15];
    const int* etyp_in = (const int*)d_in[16];
    float* out = (float*)d_out;

    const int N = in_sizes[0] / 128;
    const int E = in_sizes[14];
    const int RD = in_sizes[1];  // R*64

    // ---- carve workspace ----
    char* p = (char*)d_ws;
    auto alloc = [&](size_t bytes) -> void* {
        void* r = (void*)p;
        p += (bytes + 255) & ~(size_t)255;
        return r;
    };
    float* cost = (float*)alloc((size_t)RD * 4);
    float* sint = (float*)alloc((size_t)RD * 4);
    float* ews = (float*)alloc((size_t)E * 4);
    int* esrc = (int*)alloc((size_t)E * 4);
    int* etyp = (int*)alloc((size_t)E * 4);
    int* deg = (int*)alloc((size_t)N * 4);
    int* cur = (int*)alloc((size_t)N * 4);
    int* incl = (int*)alloc((size_t)N * 4);
    int* offs = (int*)alloc((size_t)(N + 1) * 4);
    int* bsum = (int*)alloc(512);
    int* bbase = (int*)alloc(512);
    float* side = (float*)alloc((size_t)N * 128 * 4);
    float* ego1 = (float*)alloc((size_t)N * 64 * 4);
    float* ego2 = (float*)alloc((size_t)N * 32 * 4);
    float* ego3 = (float*)alloc((size_t)N * 16 * 4);

    // ---- zero atomic counters (ws is poisoned each launch) ----
    hipMemsetAsync(deg, 0, (size_t)N * 4, stream);
    hipMemsetAsync(cur, 0, (size_t)N * 4, stream);

    // ---- cos/sin tables ----
    cossin_kernel<<<(RD + 255) / 256, 256, 0, stream>>>(rel, cost, sint, RD);

    // ---- CSR build ----
    hist_kernel<<<(E + 255) / 256, 256, 0, stream>>>(edst_in, deg, E);
    int nb1 = (N + 1023) / 1024;
    scan_partial<<<nb1, 1024, 0, stream>>>(deg, incl, bsum, N);
    scan_bsums<<<1, 128, 0, stream>>>(bsum, bbase, nb1);
    scan_final<<<nb1, 1024, 0, stream>>>(incl, bbase, offs, N);
    fill_kernel<<<(E + 255) / 256, 256, 0, stream>>>(esrc_in, edst_in, etyp_in, offs, cur, esrc, etyp, E);

    // ---- fused attention + softmax + layer-0 side (single gather pass) ----
    fused_att_kernel<<<(N + 3) / 4, 256, 0, stream>>>(ent, cost, sint, offs, esrc, etyp, ews, side, N);

    // ---- layer 0: din=128, dout=64 ----
    layer_kernel<128, 64><<<3072, 256, 0, stream>>>(ent, side, W1_0, b1_0, W2_0, b2_0, ego1, out, 128, N);

    // ---- layer 1: din=64, dout=32 ----
    side64_kernel<<<(N + 3) / 4, 256, 0, stream>>>(ego1, ews, esrc, offs, side, N);
    layer_kernel<64, 32><<<3072, 256, 0, stream>>>(ego1, side, W1_1, b1_1, W2_1, b2_1, ego2, out, 192, N);

    // ---- layer 2: din=32, dout=16 ----
    side32_kernel<<<(N + 3) / 4, 256, 0, stream>>>(ego2, ews, esrc, offs, side, N);
    layer_kernel<32, 16><<<3072, 256, 0, stream>>>(ego2, side, W1_2, b1_2, W2_2, b2_2, ego3, out, 224, N);

    // ---- out[:, 0:128] = ent_embed ----
    copy_ent<<<((N * 32) + 255) / 256, 256, 0, stream>>>((const float4*)ent, out, N);
}